// Round 6
// baseline (124.050 us; speedup 1.0000x reference)
//
#include <hip/hip_runtime.h>

// Problem constants (nb=16, k=11, ps=10, with_padding=1, rgb 1x3x2048x2048 f32)
constexpr int H   = 2048;
constexpr int W   = 2048;
constexpr int NB  = 16;
constexpr int K   = 11;
constexpr int PS  = 10;
constexpr int PAD = (K - 1) / 2;                 // 5
constexpr int HO  = (H + 2 * PAD - K) / PS + 1;  // 205
constexpr int WO  = (W + 2 * PAD - K) / PS + 1;  // 205
constexpr int PSP = PS + 1;                      // 11
constexpr int OH  = HO * PSP;                    // 2255
constexpr int OW  = WO * PSP;                    // 2255

constexpr int TW  = 4;                 // 4x4 windows per block
constexpr int R   = TW * PS + K - 1;   // 41 rows/cols of pixels per tile
constexpr int NF4 = 12;                // aligned float4 slots per row (covers 41 cols, gx0%4==3)
constexpr int LP  = NF4 * 4;           // 48: LDS row pitch (float4-aligned)
constexpr int NSLOT = R * NF4;         // 492 float4 slots per channel

typedef float floatx4 __attribute__((ext_vector_type(4)));   // clang vector: ok for nontemporal builtin

// Kernel 1 (unchanged from R4 — below fill-dispatch noise): one block = 4x4
// window tile. Aligned float4 staging into LDS, 16 threads/window,
// register-cached pixels, packed-u64 histogram, shfl_xor(16) reduce,
// first-tie-wins argmax, conditional sums. Exact IEEE (r+g+b)/3.0f kept for
// absmax == 0.
__global__ __launch_bounds__(256) void window_kernel(const float* __restrict__ rgb,
                                                     float* __restrict__ val) {
    __shared__ float ls_r[R * LP];
    __shared__ float ls_g[R * LP];
    __shared__ float ls_b[R * LP];

    int tid = threadIdx.x;
    int wy0 = blockIdx.y * TW;
    int wx0 = blockIdx.x * TW;
    int gy0 = wy0 * PS - PAD;
    int gx0 = wx0 * PS - PAD;          // == 3 (mod 4) for every block
    int f0  = gx0 >> 2;                // floor div (gx0 may be -5)

    const float* __restrict__ rp = rgb;
    const float* __restrict__ gp = rgb + H * W;
    const float* __restrict__ bp = rgb + 2 * H * W;

    const float4 SENT = make_float4(1.0e9f, 1.0e9f, 1.0e9f, 1.0e9f);
    for (int s = tid; s < NSLOT; s += 256) {
        int row = s / NF4;
        int f   = s - row * NF4;
        int y   = gy0 + row;
        int fg  = f0 + f;
        float4 r4 = SENT, g4 = SENT, b4 = SENT;
        if ((unsigned)y < (unsigned)H && (unsigned)fg < (unsigned)(W / 4)) {
            long o = (long)y * W + (fg << 2);
            r4 = *(const float4*)(rp + o);
            g4 = *(const float4*)(gp + o);
            b4 = *(const float4*)(bp + o);
        }
        int la = row * LP + (f << 2);
        *(float4*)(ls_r + la) = r4;
        *(float4*)(ls_g + la) = g4;
        *(float4*)(ls_b + la) = b4;
    }
    __syncthreads();

    int wid = tid >> 4;
    int sub = tid & 15;
    int wly = wid >> 2, wlx = wid & 3;
    int wy = wy0 + wly, wx = wx0 + wlx;
    bool valid = (wy < HO) && (wx < WO);
    int base = (wly * PS) * LP + (wlx * PS) + 3;

    float cr[8], cg[8], cb[8];
    int   ci[8];
    unsigned long long lo = 0ull, hi = 0ull;
    #pragma unroll
    for (int t = 0; t < 8; ++t) {
        int p = sub + 16 * t;
        float r = 0.f, g = 0.f, b = 0.f;
        int idx = 9999;
        if (p < K * K) {
            int j = p / K, i = p - j * K;
            int addr = base + j * LP + i;
            r = ls_r[addr]; g = ls_g[addr]; b = ls_b[addr];
            float mean = (r + g + b) / 3.0f;     // exact IEEE, matches np
            idx = (int)(mean * 0.0625f);
        }
        cr[t] = r; cg[t] = g; cb[t] = b; ci[t] = idx;
        if ((unsigned)idx < 8u)       lo += 1ull << (idx * 8);
        else if ((unsigned)idx < 16u) hi += 1ull << ((idx - 8) * 8);
    }
    #pragma unroll
    for (int s = 1; s < 16; s <<= 1) {
        lo += __shfl_xor(lo, s, 16);
        hi += __shfl_xor(hi, s, 16);
    }

    int best = 0;
    int bestc = (int)(lo & 0xffull);
    #pragma unroll
    for (int b = 1; b < NB; ++b) {
        unsigned long long wsel = (b < 8) ? lo : hi;
        int c = (int)((wsel >> ((b & 7) * 8)) & 0xffull);
        if (c > bestc) { bestc = c; best = b; }
    }

    float sr = 0.f, sg = 0.f, sb = 0.f;
    #pragma unroll
    for (int t = 0; t < 8; ++t) {
        if (ci[t] == best) { sr += cr[t]; sg += cg[t]; sb += cb[t]; }
    }
    #pragma unroll
    for (int s = 1; s < 16; s <<= 1) {
        sr += __shfl_xor(sr, s, 16);
        sg += __shfl_xor(sg, s, 16);
        sb += __shfl_xor(sb, s, 16);
    }

    if (sub == 0 && valid) {
        float cm = (float)bestc;
        int o = wy * WO + wx;
        val[o]               = sr / cm;
        val[HO * WO + o]     = sg / cm;
        val[2 * HO * WO + o] = sb / cm;
    }
}

// Kernel 2: one block per output row. Row->(channel,by,iy) is block-uniform.
// val row staged in LDS. Stores are ALIGNED float4 nontemporal for the bulk
// (row base = row*2255 ≡ row*3 mod 4 -> peel <=3-elem scalar head/tail).
// 4x fewer store instructions than R4; WRITE_SIZE stays exactly 61 MB.
__global__ __launch_bounds__(256) void write_kernel(const float* __restrict__ val,
                                                    float* __restrict__ out) {
    int row = blockIdx.x;              // 0 .. 3*OH-1
    int c   = row / OH;
    int y   = row - c * OH;
    int by  = y / PSP;
    int iy  = y - by * PSP;
    bool zrow = (iy == PS);

    __shared__ float lv[WO];
    if (threadIdx.x < WO)
        lv[threadIdx.x] = zrow ? 0.0f : val[c * HO * WO + by * WO + threadIdx.x];
    __syncthreads();

    long base = (long)row * OW;        // element index of row start
    int  mis  = (int)(base & 3);       // row start misalignment (elements)
    int  lead = (4 - mis) & 3;         // scalar elements before 16B-aligned bulk
    int  n4   = (OW - lead) >> 2;      // aligned float4 count
    int  tail = OW - lead - (n4 << 2); // trailing scalar elements (<=3)

    // head + tail scalars (at most 6 elements -> first 8 threads)
    if (threadIdx.x < 8) {
        int e = threadIdx.x;
        int x = (e < lead) ? e : (e - lead < tail ? lead + (n4 << 2) + (e - lead) : -1);
        if (x >= 0) {
            int bx = (int)((unsigned)x / (unsigned)PSP);
            int ix = x - bx * PSP;
            float v = (zrow || ix == PS) ? 0.0f : lv[bx];
            out[base + x] = v;
        }
    }

    // aligned bulk: float4 nontemporal stores
    for (int q = threadIdx.x; q < n4; q += 256) {
        int x0 = lead + (q << 2);
        floatx4 vv;
        #pragma unroll
        for (int e = 0; e < 4; ++e) {
            int x  = x0 + e;
            int bx = (int)((unsigned)x / (unsigned)PSP);   // magic-mul
            int ix = x - bx * PSP;
            vv[e] = (zrow || ix == PS) ? 0.0f : lv[bx];
        }
        __builtin_nontemporal_store(vv, (floatx4*)(out + base + x0));
    }
}

extern "C" void kernel_launch(void* const* d_in, const int* in_sizes, int n_in,
                              void* d_out, int out_size, void* d_ws, size_t ws_size,
                              hipStream_t stream) {
    const float* rgb = (const float*)d_in[0];
    float* val = (float*)d_ws;         // 3*205*205 floats = 504,300 B scratch
    float* out = (float*)d_out;

    dim3 grid1((WO + TW - 1) / TW, (HO + TW - 1) / TW);   // 52 x 52 = 2704
    window_kernel<<<grid1, 256, 0, stream>>>(rgb, val);

    write_kernel<<<3 * OH, 256, 0, stream>>>(val, out);   // 6765 blocks
}

// Round 7
// 122.104 us; speedup vs baseline: 1.0159x; 1.0159x over previous
//
#include <hip/hip_runtime.h>

// Problem constants (nb=16, k=11, ps=10, with_padding=1, rgb 1x3x2048x2048 f32)
constexpr int H   = 2048;
constexpr int W   = 2048;
constexpr int NB  = 16;
constexpr int K   = 11;
constexpr int PS  = 10;
constexpr int PAD = (K - 1) / 2;                 // 5
constexpr int HO  = (H + 2 * PAD - K) / PS + 1;  // 205
constexpr int WO  = (W + 2 * PAD - K) / PS + 1;  // 205
constexpr int PSP = PS + 1;                      // 11
constexpr int OH  = HO * PSP;                    // 2255
constexpr int OW  = WO * PSP;                    // 2255

constexpr int TW  = 4;                 // 4x4 windows per block
constexpr int R   = TW * PS + K - 1;   // 41 rows/cols of pixels per tile
constexpr int NF4 = 12;                // aligned float4 slots per row (covers 41 cols, gx0%4==3)
constexpr int LP  = NF4 * 4;           // 48: LDS row pitch (floats, float4-aligned)
constexpr int NSLOT = R * NF4;         // 492 float4 slots per channel

typedef float floatx4 __attribute__((ext_vector_type(4)));

#if __has_builtin(__builtin_amdgcn_global_load_lds)
#define HAVE_GLL 1
typedef const __attribute__((address_space(1))) void* gas_ptr;
typedef __attribute__((address_space(3))) void* las_ptr;
#else
#define HAVE_GLL 0
#endif

// Kernel 1: one block = 4x4 window tile. Interior blocks (92%) stage the
// 41-row x 12-float4 rgb region via global_load_lds dwordx4 (direct HBM->LDS
// DMA, no VGPR round trip; LDS layout is slot-contiguous = wave-uniform base +
// lane*16, exactly the builtin's constraint). Edge blocks use the float4 +
// sentinel path. Then 16 threads/window, register-cached pixels, packed-u64
// histogram, shfl_xor(16) reduce, first-tie-wins argmax, conditional sums.
// Exact IEEE (r+g+b)/3.0f kept for absmax == 0.
__global__ __launch_bounds__(256) void window_kernel(const float* __restrict__ rgb,
                                                     float* __restrict__ val) {
    __shared__ float ls_r[R * LP];
    __shared__ float ls_g[R * LP];
    __shared__ float ls_b[R * LP];

    int tid = threadIdx.x;
    int wy0 = blockIdx.y * TW;
    int wx0 = blockIdx.x * TW;
    int gy0 = wy0 * PS - PAD;
    int gx0 = wx0 * PS - PAD;          // == 3 (mod 4) for every block
    int f0  = gx0 >> 2;                // floor div (gx0 may be -5); 10*bx - 2

    const float* __restrict__ rp = rgb;
    const float* __restrict__ gp = rgb + H * W;
    const float* __restrict__ bp = rgb + 2 * H * W;

    // interior iff the whole 41x48 footprint is in-bounds: bx,by in [1,50]
    bool interior = (blockIdx.x >= 1) && (blockIdx.x <= 50) &&
                    (blockIdx.y >= 1) && (blockIdx.y <= 50);

#if HAVE_GLL
    if (interior) {
        int wv = tid >> 6;             // wave id (block-uniform per wave)
        #pragma unroll
        for (int k = 0; k < 2; ++k) {
            int s     = k * 256 + tid;       // per-lane float4 slot
            int sbase = k * 256 + wv * 64;   // wave-uniform slot base
            if (sbase < NSLOT) {
                if (s < NSLOT) {
                    int row = s / NF4, f = s - row * NF4;
                    long go = (long)(gy0 + row) * W + ((f0 + f) << 2);
                    __builtin_amdgcn_global_load_lds((gas_ptr)(rp + go),
                                                     (las_ptr)(ls_r + sbase * 4), 16, 0, 0);
                    __builtin_amdgcn_global_load_lds((gas_ptr)(gp + go),
                                                     (las_ptr)(ls_g + sbase * 4), 16, 0, 0);
                    __builtin_amdgcn_global_load_lds((gas_ptr)(bp + go),
                                                     (las_ptr)(ls_b + sbase * 4), 16, 0, 0);
                }
            }
        }
    } else
#endif
    {
        const float4 SENT = make_float4(1.0e9f, 1.0e9f, 1.0e9f, 1.0e9f);
        for (int s = tid; s < NSLOT; s += 256) {
            int row = s / NF4;
            int f   = s - row * NF4;
            int y   = gy0 + row;
            int fg  = f0 + f;
            float4 r4 = SENT, g4 = SENT, b4 = SENT;
            if ((unsigned)y < (unsigned)H && (unsigned)fg < (unsigned)(W / 4)) {
                long o = (long)y * W + (fg << 2);
                r4 = *(const float4*)(rp + o);
                g4 = *(const float4*)(gp + o);
                b4 = *(const float4*)(bp + o);
            }
            int la = row * LP + (f << 2);
            *(float4*)(ls_r + la) = r4;
            *(float4*)(ls_g + la) = g4;
            *(float4*)(ls_b + la) = b4;
        }
    }
    __syncthreads();   // drains vmcnt (incl. global_load_lds) + lgkmcnt

    int wid = tid >> 4;
    int sub = tid & 15;
    int wly = wid >> 2, wlx = wid & 3;
    int wy = wy0 + wly, wx = wx0 + wlx;
    bool valid = (wy < HO) && (wx < WO);
    int base = (wly * PS) * LP + (wlx * PS) + 3;   // tile col c -> LDS col c+3

    float cr[8], cg[8], cb[8];
    int   ci[8];
    unsigned long long lo = 0ull, hi = 0ull;
    #pragma unroll
    for (int t = 0; t < 8; ++t) {
        int p = sub + 16 * t;
        float r = 0.f, g = 0.f, b = 0.f;
        int idx = 9999;
        if (p < K * K) {
            int j = p / K, i = p - j * K;
            int addr = base + j * LP + i;
            r = ls_r[addr]; g = ls_g[addr]; b = ls_b[addr];
            float mean = (r + g + b) / 3.0f;     // exact IEEE, matches np
            idx = (int)(mean * 0.0625f);
        }
        cr[t] = r; cg[t] = g; cb[t] = b; ci[t] = idx;
        if ((unsigned)idx < 8u)       lo += 1ull << (idx * 8);
        else if ((unsigned)idx < 16u) hi += 1ull << ((idx - 8) * 8);
    }
    #pragma unroll
    for (int s = 1; s < 16; s <<= 1) {
        lo += __shfl_xor(lo, s, 16);
        hi += __shfl_xor(hi, s, 16);
    }

    int best = 0;
    int bestc = (int)(lo & 0xffull);
    #pragma unroll
    for (int b = 1; b < NB; ++b) {
        unsigned long long wsel = (b < 8) ? lo : hi;
        int c = (int)((wsel >> ((b & 7) * 8)) & 0xffull);
        if (c > bestc) { bestc = c; best = b; }
    }

    float sr = 0.f, sg = 0.f, sb = 0.f;
    #pragma unroll
    for (int t = 0; t < 8; ++t) {
        if (ci[t] == best) { sr += cr[t]; sg += cg[t]; sb += cb[t]; }
    }
    #pragma unroll
    for (int s = 1; s < 16; s <<= 1) {
        sr += __shfl_xor(sr, s, 16);
        sg += __shfl_xor(sg, s, 16);
        sb += __shfl_xor(sb, s, 16);
    }

    if (sub == 0 && valid) {
        float cm = (float)bestc;
        int o = wy * WO + wx;
        val[o]               = sr / cm;
        val[HO * WO + o]     = sg / cm;
        val[2 * HO * WO + o] = sb / cm;
    }
}

// Kernel 2 (unchanged from R6): one block per output row; val row staged in
// LDS; aligned float4 nontemporal bulk stores + <=3-elem scalar head/tail.
__global__ __launch_bounds__(256) void write_kernel(const float* __restrict__ val,
                                                    float* __restrict__ out) {
    int row = blockIdx.x;              // 0 .. 3*OH-1
    int c   = row / OH;
    int y   = row - c * OH;
    int by  = y / PSP;
    int iy  = y - by * PSP;
    bool zrow = (iy == PS);

    __shared__ float lv[WO];
    if (threadIdx.x < WO)
        lv[threadIdx.x] = zrow ? 0.0f : val[c * HO * WO + by * WO + threadIdx.x];
    __syncthreads();

    long base = (long)row * OW;
    int  mis  = (int)(base & 3);
    int  lead = (4 - mis) & 3;
    int  n4   = (OW - lead) >> 2;
    int  tail = OW - lead - (n4 << 2);

    if (threadIdx.x < 8) {
        int e = threadIdx.x;
        int x = (e < lead) ? e : (e - lead < tail ? lead + (n4 << 2) + (e - lead) : -1);
        if (x >= 0) {
            int bx = (int)((unsigned)x / (unsigned)PSP);
            int ix = x - bx * PSP;
            float v = (zrow || ix == PS) ? 0.0f : lv[bx];
            out[base + x] = v;
        }
    }

    for (int q = threadIdx.x; q < n4; q += 256) {
        int x0 = lead + (q << 2);
        floatx4 vv;
        #pragma unroll
        for (int e = 0; e < 4; ++e) {
            int x  = x0 + e;
            int bx = (int)((unsigned)x / (unsigned)PSP);
            int ix = x - bx * PSP;
            vv[e] = (zrow || ix == PS) ? 0.0f : lv[bx];
        }
        __builtin_nontemporal_store(vv, (floatx4*)(out + base + x0));
    }
}

extern "C" void kernel_launch(void* const* d_in, const int* in_sizes, int n_in,
                              void* d_out, int out_size, void* d_ws, size_t ws_size,
                              hipStream_t stream) {
    const float* rgb = (const float*)d_in[0];
    float* val = (float*)d_ws;         // 3*205*205 floats = 504,300 B scratch
    float* out = (float*)d_out;

    dim3 grid1((WO + TW - 1) / TW, (HO + TW - 1) / TW);   // 52 x 52 = 2704
    window_kernel<<<grid1, 256, 0, stream>>>(rgb, val);

    write_kernel<<<3 * OH, 256, 0, stream>>>(val, out);   // 6765 blocks
}

// Round 8
// 120.445 us; speedup vs baseline: 1.0299x; 1.0138x over previous
//
#include <hip/hip_runtime.h>

// Problem constants (nb=16, k=11, ps=10, with_padding=1, rgb 1x3x2048x2048 f32)
constexpr int H   = 2048;
constexpr int W   = 2048;
constexpr int NB  = 16;
constexpr int K   = 11;
constexpr int PS  = 10;
constexpr int PAD = (K - 1) / 2;                 // 5
constexpr int HO  = (H + 2 * PAD - K) / PS + 1;  // 205
constexpr int WO  = (W + 2 * PAD - K) / PS + 1;  // 205
constexpr int PSP = PS + 1;                      // 11
constexpr int OH  = HO * PSP;                    // 2255
constexpr int OW  = WO * PSP;                    // 2255

constexpr int TW  = 4;                       // 4x4 windows per block
constexpr int R   = (TW - 1) * PS + K;       // 41 rows actually needed (was 50: bug)
constexpr int NF4 = 11;                      // float4 slots/row: [gx0-3, gx0+41) covers cols 0..40
constexpr int LP  = NF4 * 4;                 // 44 floats LDS row pitch (16B-aligned: 176 B)
constexpr int NSLOT = R * NF4;               // 451 float4 slots per channel
// LDS: 3 * 41 * 44 * 4 B = 21.6 KB -> 7 blocks/CU

typedef float floatx4 __attribute__((ext_vector_type(4)));

#if __has_builtin(__builtin_amdgcn_global_load_lds)
#define HAVE_GLL 1
typedef const __attribute__((address_space(1))) void* gas_ptr;
typedef __attribute__((address_space(3))) void* las_ptr;
#else
#define HAVE_GLL 0
#endif

// Integer binning, bit-equivalent to (int)(fl(fl(s/3))*0.0625f):
//   idx >= k  <=>  fl(s/3) >= 16k  <=>  s >= 48k  (48k integer, exact fp32;
//   boundary rounding proven: ulp(48k)/3 > spacing_below(16k)/2)
//   =>  idx = trunc_u32(s) / 48   (cvt + magic-mul, no IEEE div chain)
__device__ __forceinline__ int bin_of(float s) {
    return (int)((unsigned)s / 48u);
}

// Kernel 1: one block = 4x4 window tile. Interior blocks (92%) stage the
// 41-row x 11-float4 rgb region via global_load_lds dwordx4 (HBM->LDS DMA,
// slot-contiguous layout = wave-uniform base + lane*16). Edge blocks use
// float4 + sentinel. 16 threads/window, register-cached pixels, packed-u64
// histogram, shfl_xor(16) reduce, first-tie-wins argmax, conditional sums.
__global__ __launch_bounds__(256) void window_kernel(const float* __restrict__ rgb,
                                                     float* __restrict__ val) {
    __shared__ float ls_r[R * LP];
    __shared__ float ls_g[R * LP];
    __shared__ float ls_b[R * LP];

    int tid = threadIdx.x;
    int wy0 = blockIdx.y * TW;
    int wx0 = blockIdx.x * TW;
    int gy0 = wy0 * PS - PAD;
    int gx0 = wx0 * PS - PAD;          // == 3 (mod 4) for every block
    int f0  = gx0 >> 2;                // floor div (gx0 may be -5): 10*bx - 2

    const float* __restrict__ rp = rgb;
    const float* __restrict__ gp = rgb + H * W;
    const float* __restrict__ bp = rgb + 2 * H * W;

    // interior iff whole 41x44 footprint in-bounds:
    //   x: [40bx-8, 40bx+36) -> bx in [1,50];  y: [40by-5, 40by+36) -> by in [1,50]
    bool interior = (blockIdx.x >= 1) && (blockIdx.x <= 50) &&
                    (blockIdx.y >= 1) && (blockIdx.y <= 50);

#if HAVE_GLL
    if (interior) {
        int wv = tid >> 6;             // wave id (block-uniform per wave)
        #pragma unroll
        for (int k = 0; k < 2; ++k) {
            int s     = k * 256 + tid;       // per-lane float4 slot (0..450)
            int sbase = k * 256 + wv * 64;   // wave-uniform slot base
            if (sbase < NSLOT && s < NSLOT) {
                int row = s / NF4, f = s - row * NF4;
                long go = (long)(gy0 + row) * W + ((f0 + f) << 2);
                __builtin_amdgcn_global_load_lds((gas_ptr)(rp + go),
                                                 (las_ptr)(ls_r + sbase * 4), 16, 0, 0);
                __builtin_amdgcn_global_load_lds((gas_ptr)(gp + go),
                                                 (las_ptr)(ls_g + sbase * 4), 16, 0, 0);
                __builtin_amdgcn_global_load_lds((gas_ptr)(bp + go),
                                                 (las_ptr)(ls_b + sbase * 4), 16, 0, 0);
            }
        }
    } else
#endif
    {
        const float4 SENT = make_float4(1.0e9f, 1.0e9f, 1.0e9f, 1.0e9f);
        for (int s = tid; s < NSLOT; s += 256) {
            int row = s / NF4;
            int f   = s - row * NF4;
            int y   = gy0 + row;
            int fg  = f0 + f;
            float4 r4 = SENT, g4 = SENT, b4 = SENT;
            if ((unsigned)y < (unsigned)H && (unsigned)fg < (unsigned)(W / 4)) {
                long o = (long)y * W + (fg << 2);
                r4 = *(const float4*)(rp + o);
                g4 = *(const float4*)(gp + o);
                b4 = *(const float4*)(bp + o);
            }
            int la = row * LP + (f << 2);
            *(float4*)(ls_r + la) = r4;
            *(float4*)(ls_g + la) = g4;
            *(float4*)(ls_b + la) = b4;
        }
    }
    __syncthreads();   // drains vmcnt (incl. global_load_lds) + lgkmcnt

    int wid = tid >> 4;
    int sub = tid & 15;
    int wly = wid >> 2, wlx = wid & 3;
    int wy = wy0 + wly, wx = wx0 + wlx;
    bool valid = (wy < HO) && (wx < WO);
    int base = (wly * PS) * LP + (wlx * PS) + 3;   // tile col c -> LDS col c+3

    float cr[8], cg[8], cb[8];
    int   ci[8];
    unsigned long long lo = 0ull, hi = 0ull;
    #pragma unroll
    for (int t = 0; t < 8; ++t) {
        int p = sub + 16 * t;          // t<7: p<121 always; t==7 valid iff sub<9
        float r = 0.f, g = 0.f, b = 0.f;
        int idx = 1 << 28;
        if (p < K * K) {
            int j = p / K, i = p - j * K;
            int addr = base + j * LP + i;
            r = ls_r[addr]; g = ls_g[addr]; b = ls_b[addr];
            idx = bin_of((r + g) + b);      // same fp32 sum order as reference
        }
        cr[t] = r; cg[t] = g; cb[t] = b; ci[t] = idx;
        if ((unsigned)idx < 8u)       lo += 1ull << (idx * 8);
        else if ((unsigned)idx < 16u) hi += 1ull << ((idx - 8) * 8);
    }
    #pragma unroll
    for (int s = 1; s < 16; s <<= 1) {
        lo += __shfl_xor(lo, s, 16);
        hi += __shfl_xor(hi, s, 16);
    }

    int best = 0;
    int bestc = (int)(lo & 0xffull);
    #pragma unroll
    for (int b = 1; b < NB; ++b) {
        unsigned long long wsel = (b < 8) ? lo : hi;
        int c = (int)((wsel >> ((b & 7) * 8)) & 0xffull);
        if (c > bestc) { bestc = c; best = b; }
    }

    float sr = 0.f, sg = 0.f, sb = 0.f;
    #pragma unroll
    for (int t = 0; t < 8; ++t) {
        if (ci[t] == best) { sr += cr[t]; sg += cg[t]; sb += cb[t]; }
    }
    #pragma unroll
    for (int s = 1; s < 16; s <<= 1) {
        sr += __shfl_xor(sr, s, 16);
        sg += __shfl_xor(sg, s, 16);
        sb += __shfl_xor(sb, s, 16);
    }

    if (sub == 0 && valid) {
        float cm = (float)bestc;
        int o = wy * WO + wx;
        val[o]               = sr / cm;
        val[HO * WO + o]     = sg / cm;
        val[2 * HO * WO + o] = sb / cm;
    }
}

// Kernel 2 (unchanged): one block per output row; val row staged in LDS;
// aligned float4 nontemporal bulk stores + <=3-elem scalar head/tail.
__global__ __launch_bounds__(256) void write_kernel(const float* __restrict__ val,
                                                    float* __restrict__ out) {
    int row = blockIdx.x;              // 0 .. 3*OH-1
    int c   = row / OH;
    int y   = row - c * OH;
    int by  = y / PSP;
    int iy  = y - by * PSP;
    bool zrow = (iy == PS);

    __shared__ float lv[WO];
    if (threadIdx.x < WO)
        lv[threadIdx.x] = zrow ? 0.0f : val[c * HO * WO + by * WO + threadIdx.x];
    __syncthreads();

    long base = (long)row * OW;
    int  mis  = (int)(base & 3);
    int  lead = (4 - mis) & 3;
    int  n4   = (OW - lead) >> 2;
    int  tail = OW - lead - (n4 << 2);

    if (threadIdx.x < 8) {
        int e = threadIdx.x;
        int x = (e < lead) ? e : (e - lead < tail ? lead + (n4 << 2) + (e - lead) : -1);
        if (x >= 0) {
            int bx = (int)((unsigned)x / (unsigned)PSP);
            int ix = x - bx * PSP;
            float v = (zrow || ix == PS) ? 0.0f : lv[bx];
            out[base + x] = v;
        }
    }

    for (int q = threadIdx.x; q < n4; q += 256) {
        int x0 = lead + (q << 2);
        floatx4 vv;
        #pragma unroll
        for (int e = 0; e < 4; ++e) {
            int x  = x0 + e;
            int bx = (int)((unsigned)x / (unsigned)PSP);
            int ix = x - bx * PSP;
            vv[e] = (zrow || ix == PS) ? 0.0f : lv[bx];
        }
        __builtin_nontemporal_store(vv, (floatx4*)(out + base + x0));
    }
}

extern "C" void kernel_launch(void* const* d_in, const int* in_sizes, int n_in,
                              void* d_out, int out_size, void* d_ws, size_t ws_size,
                              hipStream_t stream) {
    const float* rgb = (const float*)d_in[0];
    float* val = (float*)d_ws;         // 3*205*205 floats = 504,300 B scratch
    float* out = (float*)d_out;

    dim3 grid1((WO + TW - 1) / TW, (HO + TW - 1) / TW);   // 52 x 52 = 2704
    window_kernel<<<grid1, 256, 0, stream>>>(rgb, val);

    write_kernel<<<3 * OH, 256, 0, stream>>>(val, out);   // 6765 blocks
}